// Round 5
// baseline (292.681 us; speedup 1.0000x reference)
//
#include <hip/hip_runtime.h>
#include <math.h>

#define NB 16
#define NN 1024
#define NH 32
#define NW 32
#define ND 256
#define NPIX (NB*NH*NW)        // 16384

// output layout (floats): z_q [16,256,32,32] | kl | indices [16,32,32] | perplexity
#define ZQ_OFF  0
#define KL_OFF  4194304
#define IDX_OFF 4194305
#define PPL_OFF 4210689

#define LGAMMA_1024F 6071.2804f
#define EXP_C 4.3959832e-10f   // e^-16/256: keeps fp32 e in a safe range

// Bs: 16 rows (pixels) x 1024 f16, row stride 1040 f16 = 2080 B.
// Chunk = 16B = 8 f16; chunk index c in [0,128) stored at c ^ (row & 7).
#define BS_ROW_B 2080

typedef _Float16 f16x8 __attribute__((ext_vector_type(8)));
typedef _Float16 f16x2 __attribute__((ext_vector_type(2)));
typedef float    f32x4 __attribute__((ext_vector_type(4)));

__device__ __forceinline__ float fast_rcp(float x){ return __builtin_amdgcn_rcpf(x); }

// lgamma+digamma for a in [1, ~8]: shift by 4, Stirling at z=a+4 (z>=5).
__device__ __forceinline__ void lgamma_digamma(float a, float& lg, float& dg){
    float a1 = a + 1.f, a2 = a + 2.f, a3 = a + 3.f, z = a + 4.f;
    float p01 = a*a1, p23 = a2*a3;
    float prod = p01*p23;
    float rz = fast_rcp(z);
    float rp = fast_rcp(prod);
    float lz = __logf(z);
    float lp = __logf(prod);
    float rz2 = rz*rz;
    lg = (z - 0.5f)*lz - z + 0.918938533f
       + rz*(0.083333333f - 0.002777778f*rz2) - lp;
    float sr = ((a + a + 1.f)*p23 + (a + a + 5.f)*p01)*rp;
    dg = lz - 0.5f*rz - rz2*(0.083333333f - 0.008333333f*rz2) - sr;
}

// one element: alpha, stats accumulation, e' = (a/ln u)^2 * EXP_C (fp32)
__device__ __forceinline__ float elem(float x, float u,
                                      float& S, float& L, float& P){
    float t  = __expf(-fabsf(x));
    float a  = fmaxf(x, 0.f) + __logf(1.f + t) + 1.f;
    float lg, dg;
    lgamma_digamma(a, lg, dg);
    S += a; L += lg; P += (a - 1.f)*dg;
    float d = 1.f - u;
    float lup = -d*(1.f + d*(0.5f + d*(0.33333333f + d*(0.25f
              + d*(0.2f + d*(0.16666667f + d*0.14285714f))))));
    float lu = (d < 0.09f) ? lup : __logf(u);
    float ar = a * fast_rcp(lu);
    return ar*ar*EXP_C;
}

// ---------------------------------------------------------------------------
// k_tr: cb [1024n][256d] f32 -> cbT2[kb][d][32kk] f16 with the k-permutation
// n(K) = ((K>>1)&15) + 32*(K>>5) + 16*(K&1), K = kb*32 + kk.
// ---------------------------------------------------------------------------
__global__ __launch_bounds__(256) void k_tr(
    const float* __restrict__ cb, _Float16* __restrict__ cbT2)
{
    const int kb = blockIdx.x, d = threadIdx.x;
    _Float16 tmp[32];
#pragma unroll
    for (int kk = 0; kk < 32; ++kk){
        int n = 32*kb + ((kk >> 1) & 15) + 16*(kk & 1);
        tmp[kk] = (_Float16)cb[(size_t)n*ND + d];
    }
    _Float16* dst = cbT2 + (size_t)kb*8192 + (size_t)d*32;
#pragma unroll
    for (int i = 0; i < 4; ++i) *(f16x8*)(dst + 8*i) = *(f16x8*)&tmp[8*i];
}

// ---------------------------------------------------------------------------
// k_mega: stats (e kept in VGPRs) + normalized-sample LDS(f16) + fp32 colsum
// partials + MFMA GEMM. Block = 16 pixels; lane j (of 16) x pixel wl (of 16).
// ---------------------------------------------------------------------------
__global__ __launch_bounds__(256, 4) void k_mega(
    const float* __restrict__ logits, const float* __restrict__ noise,
    const _Float16* __restrict__ cbT2, float* __restrict__ colpart,
    float* __restrict__ klsum, float* __restrict__ out)
{
    __shared__ __align__(16) char lds[16*BS_ROW_B + 64];
    char*  bsb   = lds;
    float* klbuf = (float*)(lds + 16*BS_ROW_B);

    const int t   = threadIdx.x;
    const int row = blockIdx.x >> 1;          // b*32 + h
    const int w0  = (blockIdx.x & 1) * 16;
    const int b   = row >> 5, h = row & 31;
    const int j   = t & 15;                   // lane-in-pixel
    const int wl  = t >> 4;                   // pixel-in-block
    const int p   = row*32 + w0 + wl;

    const float* lg_p = logits + (size_t)b*(NN*NH*NW) + (size_t)j*(NH*NW)
                      + (size_t)h*NW + w0 + wl;
    const float* nz_p = noise  + (size_t)p*NN + j;

    const int wrow = wl*BS_ROW_B;
    const int swz  = wl & 7;
    const int jsub = 4*(j & 3);
    const int jc   = j >> 2;

    float ev[64];
    float S = 0.f, L = 0.f, P = 0.f, Z = 0.f;
    float mx = -1.f;
    int   idx = 0;

#pragma unroll
    for (int k2 = 0; k2 < 32; ++k2){
        float x0 = lg_p[(size_t)(32*k2)*(NH*NW)];
        float u0 = nz_p[32*k2];
        float x1 = lg_p[(size_t)(32*k2 + 16)*(NH*NW)];
        float u1 = nz_p[32*k2 + 16];
        float e0 = elem(x0, u0, S, L, P);
        float e1 = elem(x1, u1, S, L, P);
        Z += e0 + e1;
        if (e0 > mx){ mx = e0; idx = j + 32*k2; }
        if (e1 > mx){ mx = e1; idx = j + 32*k2 + 16; }
        ev[2*k2]   = e0;
        ev[2*k2+1] = e1;
    }

    // butterfly over the 16 j-lanes of this pixel
#pragma unroll
    for (int mask = 1; mask < 16; mask <<= 1){
        S += __shfl_xor(S, mask);
        L += __shfl_xor(L, mask);
        P += __shfl_xor(P, mask);
        Z += __shfl_xor(Z, mask);
        float mo = __shfl_xor(mx, mask);
        int   io = __shfl_xor(idx, mask);
        bool take = (mo > mx) || (mo == mx && io < idx);
        mx  = take ? mo : mx;
        idx = take ? io : idx;
    }

    const float zinv = fast_rcp(Z);
    if (j == 0){
        out[IDX_OFF + p] = (float)idx;
        float rS = fast_rcp(S);
        float lnS = __logf(S);
        float lgS = (S - 0.5f)*lnS - S + 0.918938533f + 0.083333333f*rS;
        float dgS = lnS - 0.5f*rS;
        klbuf[wl] = lgS - L - LGAMMA_1024F + (P - dgS*(S - 1024.f));
    }

    // normalize: s = e*zinv (fp32) -> LDS f16 (no underflow: s in [0,1]);
    // colsum partials from the fp32 values, reduced over wave's 4 pixels.
    const int wv = t >> 6;
    float* crow = colpart + (size_t)(blockIdx.x*4 + wv)*NN + j;
#pragma unroll
    for (int c = 0; c < 4; ++c){
        float v[16];
#pragma unroll
        for (int i = 0; i < 8; ++i){
            int k2 = 8*c + i;
            float s0 = ev[2*k2]*zinv;
            float s1 = ev[2*k2+1]*zinv;
            f16x2 hp; hp[0] = (_Float16)s0; hp[1] = (_Float16)s1;
            *(f16x2*)(bsb + wrow + ((((k2 << 2) | jc) ^ swz) << 4) + jsub) = hp;
            v[2*i] = s0; v[2*i+1] = s1;
        }
#pragma unroll
        for (int i = 0; i < 16; ++i){
            v[i] += __shfl_xor(v[i], 16);
            v[i] += __shfl_xor(v[i], 32);
        }
        if ((t & 48) == 0){
#pragma unroll
            for (int i = 0; i < 8; ++i){
                int k2 = 8*c + i;
                crow[32*k2]      = v[2*i];
                crow[32*k2 + 16] = v[2*i+1];
            }
        }
    }

    __syncthreads();     // Bs + klbuf visible to all
    if (t == 0){
        float s = 0.f;
#pragma unroll
        for (int i = 0; i < 16; ++i) s += klbuf[i];
        atomicAdd(klsum, s);
    }

    // ---- GEMM: D[d][p] += cbT2(d,K) * Bs(p,K), K-permuted space ----
    const int lane = t & 63;
    const int fn = lane & 15;         // pixel col / d row within tile
    const int fq = lane >> 4;
    const _Float16* aBase = cbT2 + (size_t)(64*wv + fn)*32 + fq*8;
    const char* bRow = bsb + fn*BS_ROW_B;
    const int fswz = fn & 7;

    f32x4 acc[4];
#pragma unroll
    for (int mt = 0; mt < 4; ++mt) acc[mt] = (f32x4)0.f;

    f16x8 aCur[4];
#pragma unroll
    for (int mt = 0; mt < 4; ++mt) aCur[mt] = *(const f16x8*)(aBase + mt*512);

    for (int kb = 0; kb < 32; ++kb){
        const bool more = (kb + 1) < 32;
        f16x8 aN[4];
        if (more){
#pragma unroll
            for (int mt = 0; mt < 4; ++mt)
                aN[mt] = *(const f16x8*)(aBase + (size_t)(kb+1)*8192 + mt*512);
        }
        f16x8 bf = *(const f16x8*)(bRow + ((((kb << 2) | fq) ^ fswz) << 4));
#pragma unroll
        for (int mt = 0; mt < 4; ++mt)
            acc[mt] = __builtin_amdgcn_mfma_f32_16x16x32_f16(aCur[mt], bf, acc[mt], 0, 0, 0);
        if (more){
#pragma unroll
            for (int mt = 0; mt < 4; ++mt) aCur[mt] = aN[mt];
        }
    }

    float* outp = out + (size_t)b*(ND*1024) + h*32 + w0;
#pragma unroll
    for (int mt = 0; mt < 4; ++mt){
#pragma unroll
        for (int r = 0; r < 4; ++r){
            int d = 64*wv + 16*mt + 4*fq + r;
            outp[(size_t)d*1024 + fn] = acc[mt][r];
        }
    }
}

// ---------------------------------------------------------------------------
// k_red: colsum[n] = sum over 4096 colpart rows. 64 blocks: 16 row-slices x
// 4 n-slices; 16 atomics per colsum address.
// ---------------------------------------------------------------------------
__global__ __launch_bounds__(256) void k_red(
    const float* __restrict__ colpart, float* __restrict__ colsum)
{
    const int n  = (blockIdx.x & 3)*256 + threadIdx.x;
    const int r0 = (blockIdx.x >> 2)*256;
    float s = 0.f;
#pragma unroll 8
    for (int r = 0; r < 256; ++r)
        s += colpart[(size_t)(r0 + r)*NN + n];
    atomicAdd(&colsum[n], s);
}

// ---------------------------------------------------------------------------
// k_final: kl_loss + perplexity
// ---------------------------------------------------------------------------
__global__ __launch_bounds__(256) void k_final(
    const float* __restrict__ colsum, const float* __restrict__ klsum,
    float* __restrict__ out)
{
    __shared__ float red[4];
    const int tid = threadIdx.x;
    float s = 0.f;
    for (int n = tid; n < NN; n += 256){
        float avg = colsum[n] * (1.f/16384.f);
        s += avg * logf(avg + 1e-10f);
    }
#pragma unroll
    for (int mask = 1; mask < 64; mask <<= 1) s += __shfl_xor(s, mask);
    if ((tid & 63) == 0) red[tid >> 6] = s;
    __syncthreads();
    if (tid == 0){
        float tot = red[0] + red[1] + red[2] + red[3];
        out[PPL_OFF] = expf(-tot);
        out[KL_OFF]  = 1e-3f * (klsum[0] * (1.f/16384.f));
    }
}

extern "C" void kernel_launch(void* const* d_in, const int* in_sizes, int n_in,
                              void* d_out, int out_size, void* d_ws, size_t ws_size,
                              hipStream_t stream)
{
    const float* logits = (const float*)d_in[0];
    const float* cb     = (const float*)d_in[1];
    const float* noise  = (const float*)d_in[2];
    float* out = (float*)d_out;

    float* colpart = (float*)d_ws;                       // 4096*1024 f32 = 16 MB
    float* colsum  = colpart + (size_t)4096*NN;          // 1024
    float* klsum   = colsum + NN;                        // 1
    _Float16* cbT2 = (_Float16*)(colsum + NN + 4);       // 512 KB (16B-aligned)

    hipMemsetAsync(colsum, 0, (NN + 1)*sizeof(float), stream);
    k_tr   <<<dim3(32),   256, 0, stream>>>(cb, cbT2);
    k_mega <<<dim3(1024), 256, 0, stream>>>(logits, noise, cbT2, colpart, klsum, out);
    k_red  <<<dim3(64),   256, 0, stream>>>(colpart, colsum);
    k_final<<<1, 256, 0, stream>>>(colsum, klsum, out);
}

// Round 6
// 264.211 us; speedup vs baseline: 1.1078x; 1.1078x over previous
//
#include <hip/hip_runtime.h>
#include <math.h>

#define NB 16
#define NN 1024
#define NH 32
#define NW 32
#define ND 256
#define NPIX (NB*NH*NW)        // 16384

// output layout (floats): z_q [16,256,32,32] | kl | indices [16,32,32] | perplexity
#define ZQ_OFF  0
#define KL_OFF  4194304
#define IDX_OFF 4194305
#define PPL_OFF 4210689

#define LGAMMA_1024F 6071.2804f
#define BS_ROW_B 2080          // 16 rows x 1040 f16; chunk c at (c ^ (row&7))

typedef _Float16 f16x8 __attribute__((ext_vector_type(8)));
typedef float    f32x4 __attribute__((ext_vector_type(4)));

__device__ __forceinline__ float fast_rcp(float x){ return __builtin_amdgcn_rcpf(x); }

// lgamma+digamma for a in [1, ~8]: shift by 4, Stirling at z=a+4 (z>=5).
__device__ __forceinline__ void lgamma_digamma(float a, float& lg, float& dg){
    float a1 = a + 1.f, a2 = a + 2.f, a3 = a + 3.f, z = a + 4.f;
    float p01 = a*a1, p23 = a2*a3;
    float prod = p01*p23;
    float rz = fast_rcp(z);
    float rp = fast_rcp(prod);
    float lz = __logf(z);
    float lp = __logf(prod);
    float rz2 = rz*rz;
    lg = (z - 0.5f)*lz - z + 0.918938533f
       + rz*(0.083333333f - 0.002777778f*rz2) - lp;
    float sr = ((a + a + 1.f)*p23 + (a + a + 5.f)*p01)*rp;
    dg = lz - 0.5f*rz - rz2*(0.083333333f - 0.008333333f*rz2) - sr;
}

// one element: alpha, stats accumulation, e = (a/ln u)^2 (fp32, unnormalized)
__device__ __forceinline__ float elem(float x, float u,
                                      float& S, float& L, float& P){
    float t  = __expf(-fabsf(x));
    float a  = fmaxf(x, 0.f) + __logf(1.f + t) + 1.f;
    float lg, dg;
    lgamma_digamma(a, lg, dg);
    S += a; L += lg; P += (a - 1.f)*dg;
    float d = 1.f - u;
    float lup = -d*(1.f + d*(0.5f + d*(0.33333333f + d*(0.25f
              + d*(0.2f + d*(0.16666667f + d*0.14285714f))))));
    float lu = (d < 0.09f) ? lup : __logf(u);
    float ar = a * fast_rcp(lu);
    return ar*ar;
}

// ---------------------------------------------------------------------------
// k_tr: cb [1024n][256d] f32 -> cbT[kb][d][32kk] f16, natural K-order.
// ---------------------------------------------------------------------------
__global__ __launch_bounds__(256) void k_tr(
    const float* __restrict__ cb, _Float16* __restrict__ cbT)
{
    const int kb = blockIdx.x, d = threadIdx.x;
    _Float16 tmp[32];
#pragma unroll
    for (int kk = 0; kk < 32; ++kk)
        tmp[kk] = (_Float16)cb[(size_t)(32*kb + kk)*ND + d];
    _Float16* dst = cbT + (size_t)kb*8192 + (size_t)d*32;
#pragma unroll
    for (int i = 0; i < 4; ++i) *(f16x8*)(dst + 8*i) = *(f16x8*)&tmp[8*i];
}

// ---------------------------------------------------------------------------
// k_mega: 512 threads, 16 pixels, 32 lanes/pixel (j4 = lane>>4, wave v).
// Thread owns n = j4 + 4v + 32k, k<32 (ev[32] in VGPRs -> no spill).
// Stats -> butterfly(16,32) -> LDS cross-wave reduce -> normalized f16 Bs
// -> MFMA GEMM (8 waves x 32 d) -> colsum row from Bs.
// ---------------------------------------------------------------------------
__global__ __launch_bounds__(512, 6) void k_mega(
    const float* __restrict__ logits, const float* __restrict__ noise,
    const _Float16* __restrict__ cbT, float* __restrict__ colpart,
    float* __restrict__ klsum, float* __restrict__ out)
{
    __shared__ __align__(16) char lds[16*BS_ROW_B + 6*128*4];
    char*  bsb  = lds;
    float* redS = (float*)(lds + 16*BS_ROW_B);   // [8][16]
    float* redL = redS + 128;
    float* redP = redL + 128;
    float* redZ = redP + 128;
    float* redM = redZ + 128;
    int*   redI = (int*)(redM + 128);

    const int t    = threadIdx.x;
    const int row  = blockIdx.x >> 1;            // b*32 + h
    const int w0   = (blockIdx.x & 1) * 16;
    const int b    = row >> 5, h = row & 31;
    const int lane = t & 63;
    const int v    = t >> 6;                     // wave 0..7
    const int wl   = lane & 15;                  // pixel-in-block
    const int j4   = lane >> 4;                  // 0..3
    const int p    = row*32 + w0 + wl;
    const int n0   = j4 + 4*v;                   // n = n0 + 32k

    const float* lg_p = logits + (size_t)b*(NN*NH*NW) + (size_t)n0*(NH*NW)
                      + (size_t)h*NW + w0 + wl;
    const float* nz_p = noise  + (size_t)p*NN + n0;

    float ev[32];
    float S = 0.f, L = 0.f, P = 0.f, Z = 0.f;
    float mx = -1.f;
    int   idx = 0;

#pragma unroll
    for (int k = 0; k < 32; ++k){
        float x = lg_p[(size_t)(32*k)*(NH*NW)];
        float u = nz_p[32*k];
        float e = elem(x, u, S, L, P);
        Z += e;
        if (e > mx){ mx = e; idx = n0 + 32*k; }
        ev[k] = e;
    }

    // reduce over the 4 j4-lanes of this pixel within the wave
#pragma unroll
    for (int mask = 16; mask < 64; mask <<= 1){
        S += __shfl_xor(S, mask);
        L += __shfl_xor(L, mask);
        P += __shfl_xor(P, mask);
        Z += __shfl_xor(Z, mask);
        float mo = __shfl_xor(mx, mask);
        int   io = __shfl_xor(idx, mask);
        bool take = (mo > mx) || (mo == mx && io < idx);
        mx  = take ? mo : mx;
        idx = take ? io : idx;
    }
    if (j4 == 0){
        redS[16*v + wl] = S;  redL[16*v + wl] = L;
        redP[16*v + wl] = P;  redZ[16*v + wl] = Z;
        redM[16*v + wl] = mx; redI[16*v + wl] = idx;
    }
    __syncthreads();

    // every thread: full Z for its pixel (8 broadcast LDS reads)
    float Zt = 0.f;
#pragma unroll
    for (int q = 0; q < 8; ++q) Zt += redZ[16*q + wl];
    const float zinv = fast_rcp(Zt);

    // write normalized f16 sample to Bs.
    // n = n0+32k -> chunk c = n>>3 = 4k + (v>>1), sub = n&7 = (4v+j4)&7
    {
        char* brow = bsb + wl*BS_ROW_B;
        const int sw  = wl & 7;
        const int sub = 2*((4*v + j4) & 7);
        const int cv  = v >> 1;
#pragma unroll
        for (int k = 0; k < 32; ++k){
            _Float16 hv = (_Float16)(ev[k]*zinv);
            *(_Float16*)(brow + ((((k << 2) + cv) ^ sw) << 4) + sub) = hv;
        }
    }

    // per-pixel finalize: kl, argmax index
    if (t < 16){
        float Sa = 0.f, La = 0.f, Pa = 0.f, M = -1.f;
        int I = 0x7fffffff;
#pragma unroll
        for (int q = 0; q < 8; ++q){
            Sa += redS[16*q + t]; La += redL[16*q + t]; Pa += redP[16*q + t];
            float m = redM[16*q + t]; int i = redI[16*q + t];
            bool take = (m > M) || (m == M && i < I);
            M = take ? m : M; I = take ? i : I;
        }
        out[IDX_OFF + row*32 + w0 + t] = (float)I;
        float rS  = fast_rcp(Sa);
        float lnS = __logf(Sa);
        float lgS = (Sa - 0.5f)*lnS - Sa + 0.918938533f + 0.083333333f*rS;
        float dgS = lnS - 0.5f*rS;
        float kl = lgS - La - LGAMMA_1024F + (Pa - dgS*(Sa - 1024.f));
#pragma unroll
        for (int mask = 1; mask < 16; mask <<= 1) kl += __shfl_xor(kl, mask);
        if (t == 0) atomicAdd(klsum, kl);
    }
    __syncthreads();   // Bs complete

    // ---- GEMM: D[d][pix] = cbT(d,K)*Bs(pix,K); wave v -> d in [32v,32v+32) ----
    const _Float16* aBase = cbT + (size_t)(32*v + wl)*32 + j4*8;
    const char* bRow = bsb + wl*BS_ROW_B;
    const int fsw = wl & 7;

    f32x4 acc0 = (f32x4)0.f, acc1 = (f32x4)0.f;
    f16x8 a0 = *(const f16x8*)(aBase);
    f16x8 a1 = *(const f16x8*)(aBase + 512);

    for (int kb = 0; kb < 32; ++kb){
        const bool more = (kb + 1) < 32;
        f16x8 a0n, a1n;
        if (more){
            a0n = *(const f16x8*)(aBase + (size_t)(kb+1)*8192);
            a1n = *(const f16x8*)(aBase + (size_t)(kb+1)*8192 + 512);
        }
        f16x8 bf = *(const f16x8*)(bRow + ((((kb << 2) | j4) ^ fsw) << 4));
        acc0 = __builtin_amdgcn_mfma_f32_16x16x32_f16(a0, bf, acc0, 0, 0, 0);
        acc1 = __builtin_amdgcn_mfma_f32_16x16x32_f16(a1, bf, acc1, 0, 0, 0);
        if (more){ a0 = a0n; a1 = a1n; }
    }

    float* outp = out + (size_t)b*(ND*1024) + h*32 + w0;
#pragma unroll
    for (int r = 0; r < 4; ++r){
        int d = 32*v + 4*j4 + r;
        outp[(size_t)d*1024 + wl]        = acc0[r];
        outp[(size_t)(d + 16)*1024 + wl] = acc1[r];
    }

    // ---- colsum row for this block: thread t sums cols t and t+512 ----
    {
        float s0 = 0.f, s1 = 0.f;
        const int c0 = t, c1 = t + 512;
#pragma unroll
        for (int r = 0; r < 16; ++r){
            const char* br = bsb + r*BS_ROW_B;
            const int sw2 = r & 7;
            s0 += (float)*(const _Float16*)(br + ((((c0 >> 3) ^ sw2) << 4) + 2*(c0 & 7)));
            s1 += (float)*(const _Float16*)(br + ((((c1 >> 3) ^ sw2) << 4) + 2*(c1 & 7)));
        }
        float* cp = colpart + (size_t)blockIdx.x*NN;
        cp[c0] = s0;
        cp[c1] = s1;
    }
}

// ---------------------------------------------------------------------------
// k_red: colsum[n] = sum over 1024 colpart rows. 64 blocks: 4 n-slices x
// 16 row-slices (64 rows each); 16 atomics per address.
// ---------------------------------------------------------------------------
__global__ __launch_bounds__(256) void k_red(
    const float* __restrict__ colpart, float* __restrict__ colsum)
{
    const int n  = (blockIdx.x & 3)*256 + threadIdx.x;
    const int r0 = (blockIdx.x >> 2)*64;
    float s = 0.f;
#pragma unroll 8
    for (int r = 0; r < 64; ++r)
        s += colpart[(size_t)(r0 + r)*NN + n];
    atomicAdd(&colsum[n], s);
}

// ---------------------------------------------------------------------------
// k_final: kl_loss + perplexity
// ---------------------------------------------------------------------------
__global__ __launch_bounds__(256) void k_final(
    const float* __restrict__ colsum, const float* __restrict__ klsum,
    float* __restrict__ out)
{
    __shared__ float red[4];
    const int tid = threadIdx.x;
    float s = 0.f;
    for (int n = tid; n < NN; n += 256){
        float avg = colsum[n] * (1.f/16384.f);
        s += avg * logf(avg + 1e-10f);
    }
#pragma unroll
    for (int mask = 1; mask < 64; mask <<= 1) s += __shfl_xor(s, mask);
    if ((tid & 63) == 0) red[tid >> 6] = s;
    __syncthreads();
    if (tid == 0){
        float tot = red[0] + red[1] + red[2] + red[3];
        out[PPL_OFF] = expf(-tot);
        out[KL_OFF]  = 1e-3f * (klsum[0] * (1.f/16384.f));
    }
}

extern "C" void kernel_launch(void* const* d_in, const int* in_sizes, int n_in,
                              void* d_out, int out_size, void* d_ws, size_t ws_size,
                              hipStream_t stream)
{
    const float* logits = (const float*)d_in[0];
    const float* cb     = (const float*)d_in[1];
    const float* noise  = (const float*)d_in[2];
    float* out = (float*)d_out;

    float* colpart = (float*)d_ws;                       // 1024*1024 f32 = 4 MB
    float* colsum  = colpart + (size_t)1024*NN;          // 1024
    float* klsum   = colsum + NN;                        // 1
    _Float16* cbT  = (_Float16*)(klsum + 3);             // 512 KB (16B-aligned)

    hipMemsetAsync(colsum, 0, (NN + 1)*sizeof(float), stream);
    k_tr   <<<dim3(32),   256, 0, stream>>>(cb, cbT);
    k_mega <<<dim3(1024), 512, 0, stream>>>(logits, noise, cbT, colpart, klsum, out);
    k_red  <<<dim3(64),   256, 0, stream>>>(colpart, colsum);
    k_final<<<1, 256, 0, stream>>>(colsum, klsum, out);
}